// Round 5
// baseline (48.906 us; speedup 1.0000x reference)
//
#include <hip/hip_runtime.h>

#define NGUESS 256
#define RPB 50      // rows per block (half-chunk)
#define CPG 20      // chunks per group
#define NGROUP 50   // 1000 chunks / CPG

// AES inverse S-box: INV_SBOX[SBOX[x]] == x
__device__ __constant__ int INV_SBOXD[256] = {
   82,   9, 106, 213,  48,  54, 165,  56, 191,  64, 163, 158, 129, 243, 215, 251,
  124, 227,  57, 130, 155,  47, 255, 135,  52, 142,  67,  68, 196, 222, 233, 203,
   84, 123, 148,  50, 166, 194,  35,  61, 238,  76, 149,  11,  66, 250, 195,  78,
    8,  46, 161, 102,  40, 217,  36, 178, 118,  91, 162,  73, 109, 139, 209,  37,
  114, 248, 246, 100, 134, 104, 152,  22, 212, 164,  92, 204,  93, 101, 182, 146,
  108, 112,  72,  80, 253, 237, 185, 218,  94,  21,  70,  87, 167, 141, 157, 132,
  144, 216, 171,   0, 140, 188, 211,  10, 247, 228,  88,   5, 184, 179,  69,   6,
  208,  44,  30, 143, 202,  63,  15,   2, 193, 175, 189,   3,   1,  19, 138, 107,
   58, 145,  17,  65,  79, 103, 220, 234, 151, 242, 207, 206, 240, 180, 230, 115,
  150, 172, 116,  34, 231, 173,  53, 133, 226, 249,  55, 232,  28, 117, 223, 110,
   71, 241,  26, 113,  29,  41, 197, 137, 111, 183,  98,  14, 170,  24, 190,  27,
  252,  86,  62,  75, 198, 210, 121,  32, 154, 219, 192, 254, 120, 205,  90, 244,
   31, 221, 168,  51, 136,   7, 199,  49, 177,  18,  16,  89,  39, 128, 236,  95,
   96,  81, 127, 169,  25, 181,  74,  13,  45, 229, 122, 159, 147, 201, 156, 239,
  160, 224,  59,  77, 174,  42, 245, 176, 200, 235, 187,  60, 131,  83, 153,  97,
   23,  43,   4, 126, 186, 119, 214,  38, 225, 105,  20,  99,  85,  33,  12, 125
};

// K1: one block per HALF-chunk (50 rows x 256 cols) -> 2000 blocks
//     = 31 waves/CU (vs 15.6 at 1000 blocks). Wave w owns rows {w, w+4, ...}.
// Per row: coalesced float4 load -> 4 logs -> scatter into wave-private LDS
// ring slot at inv_sbox[col] (slot[p] = log(row[sbox[p]])) -> 4 structured
// reads at (mx&63)+64k (conflict-free, read2-fusable) -> cndmask XOR-select
// network resolves quadrant (VALU, not DS). No barriers in the loop.
__global__ __launch_bounds__(256) void k_halfsums(const float* __restrict__ pred,
                                                  const int* __restrict__ meta,
                                                  float* __restrict__ csh) {
  __shared__ float prow[4][2][NGUESS];  // [wave][ring][slot] 8 KB
  __shared__ float red[4][NGUESS];      // 4 KB
  __shared__ int smeta[RPB];

  const int tid = threadIdx.x;
  const int w = tid >> 6;
  const int l = tid & 63;
  const int h = blockIdx.x;                 // half-chunk id
  const size_t base = (size_t)h * RPB;

  if (tid < RPB) smeta[tid] = meta[base + tid];
  const int c0 = l << 2;
  const int t0 = INV_SBOXD[c0 + 0];
  const int t1 = INV_SBOXD[c0 + 1];
  const int t2 = INV_SBOXD[c0 + 2];
  const int t3 = INV_SBOXD[c0 + 3];
  __syncthreads();  // smeta ready

  float a0 = 0.f, a1 = 0.f, a2 = 0.f, a3 = 0.f;  // guesses l, 64+l, 128+l, 192+l
#pragma unroll 2
  for (int t = 0; t < 13; ++t) {
    const int r = w + 4 * t;
    if (r < RPB) {                           // wave-uniform
      const float4 v = *reinterpret_cast<const float4*>(pred + ((base + r) << 8) + c0);
      const int m = smeta[r];
      float* slot = prow[w][t & 1];
      slot[t0] = (v.x != 0.f) ? __logf(v.x) : 0.f;
      slot[t1] = (v.y != 0.f) ? __logf(v.y) : 0.f;
      slot[t2] = (v.z != 0.f) ? __logf(v.z) : 0.f;
      slot[t3] = (v.w != 0.f) ? __logf(v.w) : 0.f;
      const int mx = m ^ l;
      const int bse = mx & 63;               // bank = bse&31: 2 lanes/bank = free
      const int q = mx >> 6;                 // quadrant, per-lane
      const float v0 = slot[bse];
      const float v1 = slot[bse + 64];
      const float v2 = slot[bse + 128];
      const float v3 = slot[bse + 192];
      // a_j += v_{j^q}: 2-level cndmask XOR network (VALU, keeps DS pipe free)
      const bool q0 = (q & 1) != 0, q1 = (q & 2) != 0;
      const float u0 = q0 ? v1 : v0;
      const float u1 = q0 ? v0 : v1;
      const float u2 = q0 ? v3 : v2;
      const float u3 = q0 ? v2 : v3;
      a0 += q1 ? u2 : u0;
      a1 += q1 ? u3 : u1;
      a2 += q1 ? u0 : u2;
      a3 += q1 ? u1 : u3;
    }
  }

  red[w][l]       = a0;
  red[w][l + 64]  = a1;
  red[w][l + 128] = a2;
  red[w][l + 192] = a3;
  __syncthreads();
  csh[(size_t)h * NGUESS + tid] =
      red[0][tid] + red[1][tid] + red[2][tid] + red[3][tid];
}

// K2a: per-group sums over 40 half-rows, in double, dual accumulators.
__global__ __launch_bounds__(256) void k_groupsum(const float* __restrict__ csh,
                                                  double* __restrict__ gsum) {
  const int b = blockIdx.x, g = threadIdx.x;
  double s0 = 0.0, s1 = 0.0;
#pragma unroll
  for (int j = 0; j < 2 * CPG; j += 2) {
    s0 += (double)csh[(size_t)(b * 2 * CPG + j) * NGUESS + g];
    s1 += (double)csh[(size_t)(b * 2 * CPG + j + 1) * NGUESS + g];
  }
  gsum[(size_t)b * NGUESS + g] = s0 + s1;
}

// K2b: one block per chunk; prefix = masked fixed-trip unrolled loads
// (independent addresses -> fully pipelined), rank via ballot.
__global__ __launch_bounds__(256) void k_ranks(const float* __restrict__ csh,
                                               const double* __restrict__ gsum,
                                               const int* __restrict__ ckp,
                                               int* __restrict__ outRanks,
                                               int* __restrict__ outX) {
  const int c = blockIdx.x;       // chunk id
  const int g = threadIdx.x;
  const int grp = c / CPG;
  const int lim = 2 * (c - grp * CPG) + 1;  // last half-row included
  double acc = 0.0, acc2 = 0.0;
#pragma unroll
  for (int bb = 0; bb < NGROUP; ++bb)
    if (bb < grp) acc += gsum[(size_t)bb * NGUESS + g];
#pragma unroll
  for (int t = 0; t < 2 * CPG; t += 2) {
    if (t     <= lim) acc2 += (double)csh[(size_t)(grp * 2 * CPG + t)     * NGUESS + g];
    if (t + 1 <= lim) acc  += (double)csh[(size_t)(grp * 2 * CPG + t + 1) * NGUESS + g];
  }
  acc += acc2;

  __shared__ double keysh;
  __shared__ int cnt;
  const int ck = *ckp;
  if (g == ck) keysh = acc;
  if (g == 0) cnt = 0;
  __syncthreads();
  const unsigned long long mball = __ballot(acc > keysh);
  if ((g & 63) == 0) atomicAdd(&cnt, (int)__popcll(mball));
  __syncthreads();
  if (g == 0) {
    outRanks[c] = cnt;
    outX[c] = (c + 1) * 100;
  }
}

extern "C" void kernel_launch(void* const* d_in, const int* in_sizes, int n_in,
                              void* d_out, int out_size, void* d_ws, size_t ws_size,
                              hipStream_t stream) {
  const float* pred = (const float*)d_in[0];
  const int* meta   = (const int*)d_in[1];
  // d_in[2] = guess_range (256), d_in[3] = correct_key (34), d_in[4] = step (100)
  const int* ckp    = (const int*)d_in[3];

  const int N = in_sizes[1];             // 100000
  const int num_halves = N / RPB;        // 2000
  const int num_chunks = N / 100;        // 1000
  const int ngroups = num_chunks / CPG;  // 50

  float*  csh  = (float*)d_ws;                                            // [2000][256] f32
  double* gsum = (double*)((char*)d_ws +
                           (size_t)num_halves * NGUESS * sizeof(float));  // [50][256] f64

  int* out = (int*)d_out;                // ranks[0..nc), x_rank[nc..2nc)

  k_halfsums<<<num_halves, 256, 0, stream>>>(pred, meta, csh);
  k_groupsum<<<ngroups,    256, 0, stream>>>(csh, gsum);
  k_ranks   <<<num_chunks, 256, 0, stream>>>(csh, gsum, ckp, out, out + num_chunks);
}

// Round 6
// 42.732 us; speedup vs baseline: 1.1445x; 1.1445x over previous
//
#include <hip/hip_runtime.h>

#define NGUESS 256
#define CPG 20      // chunks per group
#define NGROUP 50   // 1000 chunks / CPG

// AES inverse S-box: INV_SBOX[SBOX[x]] == x
__device__ __constant__ int INV_SBOXD[256] = {
   82,   9, 106, 213,  48,  54, 165,  56, 191,  64, 163, 158, 129, 243, 215, 251,
  124, 227,  57, 130, 155,  47, 255, 135,  52, 142,  67,  68, 196, 222, 233, 203,
   84, 123, 148,  50, 166, 194,  35,  61, 238,  76, 149,  11,  66, 250, 195,  78,
    8,  46, 161, 102,  40, 217,  36, 178, 118,  91, 162,  73, 109, 139, 209,  37,
  114, 248, 246, 100, 134, 104, 152,  22, 212, 164,  92, 204,  93, 101, 182, 146,
  108, 112,  72,  80, 253, 237, 185, 218,  94,  21,  70,  87, 167, 141, 157, 132,
  144, 216, 171,   0, 140, 188, 211,  10, 247, 228,  88,   5, 184, 179,  69,   6,
  208,  44,  30, 143, 202,  63,  15,   2, 193, 175, 189,   3,   1,  19, 138, 107,
   58, 145,  17,  65,  79, 103, 220, 234, 151, 242, 207, 206, 240, 180, 230, 115,
  150, 172, 116,  34, 231, 173,  53, 133, 226, 249,  55, 232,  28, 117, 223, 110,
   71, 241,  26, 113,  29,  41, 197, 137, 111, 183,  98,  14, 170,  24, 190,  27,
  252,  86,  62,  75, 198, 210, 121,  32, 154, 219, 192, 254, 120, 205,  90, 244,
   31, 221, 168,  51, 136,   7, 199,  49, 177,  18,  16,  89,  39, 128, 236,  95,
   96,  81, 127, 169,  25, 181,  74,  13,  45, 229, 122, 159, 147, 201, 156, 239,
  160, 224,  59,  77, 174,  42, 245, 176, 200, 235, 187,  60, 131,  83, 153,  97,
   23,  43,   4, 126, 186, 119, 214,  38, 225, 105,  20,  99,  85,  33,  12, 125
};

// K1: one block per 100x256 chunk; wave w owns rows [25w, 25w+25) (consecutive).
// Pipeline per wave, branch-free:
//   iter i: rotate prefetch regs (depth 2, clamped tail), log+scatter q_i into
//   ring slot i&3 at inv_sbox[col], then gather q_{i-1} from slot (i-1)&3 at
//   (m_{i-1}^l)+{0,64,128,192} (conflict-free). Skewing the gather one row
//   behind the scatter means its data already landed (DS is in-order), so no
//   same-iteration lgkmcnt(0) chain. No barriers until the epilogue reduce.
__global__ __launch_bounds__(256) void k_chunksums(const float* __restrict__ pred,
                                                   const int* __restrict__ meta,
                                                   float* __restrict__ cs) {
  __shared__ float prow[4][4][NGUESS];  // [wave][ring][slot] 16 KB
  __shared__ float red[4][NGUESS];      // 4 KB

  const int tid = threadIdx.x;
  const int w = tid >> 6;
  const int l = tid & 63;
  const int chunk = blockIdx.x;
  const size_t base = (size_t)chunk * 100 + (size_t)w * 25;

  const int c0 = l << 2;
  const int t0 = INV_SBOXD[c0 + 0];
  const int t1 = INV_SBOXD[c0 + 1];
  const int t2 = INV_SBOXD[c0 + 2];
  const int t3 = INV_SBOXD[c0 + 3];

  const float* rp = pred + (base << 8) + c0;

  // prime: prefetch rows 0,1; meta row 0
  float4 f0 = *reinterpret_cast<const float4*>(rp);
  float4 f1 = *reinterpret_cast<const float4*>(rp + NGUESS);
  int m_prev = meta[base];

  float a0 = 0.f, a1 = 0.f, a2 = 0.f, a3 = 0.f;

  // peeled iteration 0: write q_0, no gather
  {
    const float4 v = f0;
    f0 = f1;
    f1 = *reinterpret_cast<const float4*>(rp + 2 * NGUESS);
    float* slot = prow[w][0];
    slot[t0] = (v.x != 0.f) ? __logf(v.x) : 0.f;
    slot[t1] = (v.y != 0.f) ? __logf(v.y) : 0.f;
    slot[t2] = (v.z != 0.f) ? __logf(v.z) : 0.f;
    slot[t3] = (v.w != 0.f) ? __logf(v.w) : 0.f;
  }

#pragma unroll 4
  for (int i = 1; i < 25; ++i) {
    const float4 v = f0;
    f0 = f1;
    const int pre = (i + 2 <= 24) ? (i + 2) : 24;   // clamp: branch-free OOB guard
    f1 = *reinterpret_cast<const float4*>(rp + (size_t)pre * NGUESS);
    const int m_cur = meta[base + i];

    float* slot = prow[w][i & 3];
    slot[t0] = (v.x != 0.f) ? __logf(v.x) : 0.f;
    slot[t1] = (v.y != 0.f) ? __logf(v.y) : 0.f;
    slot[t2] = (v.z != 0.f) ? __logf(v.z) : 0.f;
    slot[t3] = (v.w != 0.f) ? __logf(v.w) : 0.f;

    // gather row i-1 (data already resident; DS in-order)
    const int mx = m_prev ^ l;
    const float* ps = prow[w][(i - 1) & 3];
    a0 += ps[mx];
    a1 += ps[mx ^ 64];
    a2 += ps[mx ^ 128];
    a3 += ps[mx ^ 192];

    m_prev = m_cur;
  }
  // drain: gather row 24
  {
    const int mx = m_prev ^ l;
    const float* ps = prow[w][24 & 3];
    a0 += ps[mx];
    a1 += ps[mx ^ 64];
    a2 += ps[mx ^ 128];
    a3 += ps[mx ^ 192];
  }

  red[w][l]       = a0;
  red[w][l + 64]  = a1;
  red[w][l + 128] = a2;
  red[w][l + 192] = a3;
  __syncthreads();
  cs[(size_t)chunk * NGUESS + tid] =
      red[0][tid] + red[1][tid] + red[2][tid] + red[3][tid];
}

// K2a: per-group (20-chunk) sums in double, dual accumulators.
__global__ __launch_bounds__(256) void k_groupsum(const float* __restrict__ cs,
                                                  double* __restrict__ gsum) {
  const int b = blockIdx.x, g = threadIdx.x;
  double s0 = 0.0, s1 = 0.0;
#pragma unroll
  for (int c = 0; c < CPG; c += 2) {
    s0 += (double)cs[(size_t)(b * CPG + c) * NGUESS + g];
    s1 += (double)cs[(size_t)(b * CPG + c + 1) * NGUESS + g];
  }
  gsum[(size_t)b * NGUESS + g] = s0 + s1;
}

// K2b: one block per chunk; group prefix (masked fixed-trip, pipelines fully)
// + intra-group chunk rows; rank via ballot.
__global__ __launch_bounds__(256) void k_ranks(const float* __restrict__ cs,
                                               const double* __restrict__ gsum,
                                               const int* __restrict__ ckp,
                                               int* __restrict__ outRanks,
                                               int* __restrict__ outX) {
  const int c = blockIdx.x;       // chunk id
  const int g = threadIdx.x;
  const int grp = c / CPG;
  const int rem = c - grp * CPG;  // chunks included within group: 0..rem
  double acc = 0.0, acc2 = 0.0;
#pragma unroll
  for (int bb = 0; bb < NGROUP; bb += 2) {
    if (bb     < grp) acc  += gsum[(size_t)bb       * NGUESS + g];
    if (bb + 1 < grp) acc2 += gsum[(size_t)(bb + 1) * NGUESS + g];
  }
#pragma unroll
  for (int t = 0; t < CPG; t += 2) {
    if (t     <= rem) acc  += (double)cs[(size_t)(grp * CPG + t)     * NGUESS + g];
    if (t + 1 <= rem) acc2 += (double)cs[(size_t)(grp * CPG + t + 1) * NGUESS + g];
  }
  acc += acc2;

  __shared__ double keysh;
  __shared__ int cnt;
  const int ck = *ckp;
  if (g == ck) keysh = acc;
  if (g == 0) cnt = 0;
  __syncthreads();
  const unsigned long long mball = __ballot(acc > keysh);
  if ((g & 63) == 0) atomicAdd(&cnt, (int)__popcll(mball));
  __syncthreads();
  if (g == 0) {
    outRanks[c] = cnt;
    outX[c] = (c + 1) * 100;
  }
}

extern "C" void kernel_launch(void* const* d_in, const int* in_sizes, int n_in,
                              void* d_out, int out_size, void* d_ws, size_t ws_size,
                              hipStream_t stream) {
  const float* pred = (const float*)d_in[0];
  const int* meta   = (const int*)d_in[1];
  // d_in[2] = guess_range (256), d_in[3] = correct_key (34), d_in[4] = step (100)
  const int* ckp    = (const int*)d_in[3];

  const int N = in_sizes[1];             // 100000
  const int num_chunks = N / 100;        // 1000
  const int ngroups = num_chunks / CPG;  // 50

  float*  cs   = (float*)d_ws;                                            // [1000][256] f32
  double* gsum = (double*)((char*)d_ws +
                           (size_t)num_chunks * NGUESS * sizeof(float));  // [50][256] f64

  int* out = (int*)d_out;                // ranks[0..nc), x_rank[nc..2nc)

  k_chunksums<<<num_chunks, 256, 0, stream>>>(pred, meta, cs);
  k_groupsum <<<ngroups,    256, 0, stream>>>(cs, gsum);
  k_ranks    <<<num_chunks, 256, 0, stream>>>(cs, gsum, ckp, out, out + num_chunks);
}